// Round 11
// baseline (961.164 us; speedup 1.0000x reference)
//
#include <hip/hip_runtime.h>
#include <hip/hip_bf16.h>
#include <type_traits>

#define SEQ_LEN 48
#define HID     96
#define NB      131072
#define MROWS   304                    // 288 gate rows + 3 W_out rows + 13 zero pad
#define ABYTES  (MROWS*HID*2)          // 58368 B of bf16 A-fragments
#define A_U4    (ABYTES/16)            // 3648 uint4 in LDS (A-fragments ONLY)
#define COEF_OFF_F (ABYTES/4)          // float index 14592 in d_ws
#define COEF_FLOATS (96*16)
#define BOUT_OFF_F (COEF_OFF_F + COEF_FLOATS)   // float idx 16128 in d_ws

typedef __attribute__((ext_vector_type(4))) float f32x4;
typedef __attribute__((ext_vector_type(8))) __bf16 bf16x8;
typedef unsigned int uint;
typedef unsigned short ushort;

// exp2-based activations: weights pre-scaled by log2e (r,z) / 2*log2e (n)
__device__ __forceinline__ float sigm2(float xp) {
    return __builtin_amdgcn_rcpf(1.f + __builtin_amdgcn_exp2f(-xp));   // inf-safe
}
__device__ __forceinline__ float tanh2(float yp) {
    return 1.f - 2.f * __builtin_amdgcn_rcpf(__builtin_amdgcn_exp2f(yp) + 1.f);  // inf-safe
}
__device__ __forceinline__ uint packbf(float a, float b) {
    ushort lo = __builtin_bit_cast(ushort, __float2bfloat16(a));
    ushort hi = __builtin_bit_cast(ushort, __float2bfloat16(b));
    return (uint)lo | ((uint)hi << 16);
}

// ---------------- weight folding (r8/r9-verified, unchanged) ----------------------------
__global__ void fold_k(const float* __restrict__ W_emb, const float* __restrict__ b_emb,
                       const float* __restrict__ W_ih,  const float* __restrict__ W_hh,
                       const float* __restrict__ b_ih,  const float* __restrict__ b_hh,
                       const float* __restrict__ W_out, const float* __restrict__ b_out,
                       void* wsv)
{
    const float L2E  = 1.44269504088896340736f;
    const float L2E2 = 2.f * L2E;
    ushort* A  = (ushort*)wsv;
    float*  CF = (float*)wsv + COEF_OFF_F;
    float*  BO = (float*)wsv + BOUT_OFF_F;
    int g = blockIdx.x * 64 + threadIdx.x;
    if (g < 3) BO[g] = b_out[g];

    auto wxe_row = [&](int gg, float* w, float& bx) {
        w[0] = w[1] = w[2] = 0.f; bx = b_ih[gg];
        for (int e = 0; e < 32; e++) {
            float wi = W_ih[gg * 32 + e];
            w[0] += wi * W_emb[e * 3 + 0];
            w[1] += wi * W_emb[e * 3 + 1];
            w[2] += wi * W_emb[e * 3 + 2];
            bx   += wi * b_emb[e];
        }
    };

    if (g < MROWS) {
        float w[3] = {0.f, 0.f, 0.f}, bx = 0.f;
        if (g < 192) wxe_row(g, w, bx);
        for (int k = 0; k < HID; k++) {
            float val;
            if      (g < 192) val = (W_hh[g * HID + k] + w[0]*W_out[0*HID+k] + w[1]*W_out[1*HID+k] + w[2]*W_out[2*HID+k]) * L2E;
            else if (g < 288) val = W_hh[g * HID + k] * L2E2;
            else if (g < 291) val = W_out[(g - 288) * HID + k];
            else              val = 0.f;
            int t = g >> 4, c = k >> 5, l = (g & 15) | (((k >> 3) & 3) << 4), i = k & 7;
            A[((t * 3 + c) * 64 + l) * 8 + i] = __builtin_bit_cast(ushort, __float2bfloat16(val));
        }
    }
    if (g < 96) {
        int j = g;
        float wn[3], bxn; wxe_row(192 + j, wn, bxn);
        float wr[3], bxr; wxe_row(j,        wr, bxr);
        float wz[3], bxz; wxe_row(96 + j,   wz, bxz);
        float quads[4][4] = {
            { wn[0]*L2E2, wn[1]*L2E2, wn[2]*L2E2, bxn*L2E2 },
            { b_hh[192 + j]*L2E2,
              (bxr + b_hh[j]      + wr[0]*b_out[0] + wr[1]*b_out[1] + wr[2]*b_out[2]) * L2E,
              (bxz + b_hh[96 + j] + wz[0]*b_out[0] + wz[1]*b_out[1] + wz[2]*b_out[2]) * L2E,
              0.f },
            { wr[0]*L2E, wr[1]*L2E, wr[2]*L2E, wz[0]*L2E },
            { wz[1]*L2E, wz[2]*L2E, 0.f, 0.f }
        };
        int qj = (j >> 2) & 3;
        float* row = CF + j * 16;
        for (int L = 0; L < 4; ++L) {
            int p = (L + qj) & 3;                  // rotate within own row: injective
            row[p * 4 + 0] = quads[L][0];
            row[p * 4 + 1] = quads[L][1];
            row[p * 4 + 2] = quads[L][2];
            row[p * 4 + 3] = quads[L][3];
        }
    }
}

// ---------------- main kernel: nt=2 (32 cols/wave), coeffs from GLOBAL (L1), A in LDS ----
__global__ __launch_bounds__(256, 2)
void gru_mfma(const float* __restrict__ last_pos, const float* __restrict__ past,
              const float* __restrict__ fut, const void* __restrict__ wsv,
              float* __restrict__ out)
{
    __shared__ uint4 sb[A_U4];                 // 58368 B: A-fragments only
    const int tid = threadIdx.x;
    const uint4* gsrc = (const uint4*)wsv;
    #pragma unroll
    for (int it = 0; it < 15; ++it) { int idx = tid + it * 256; if (idx < A_U4) sb[idx] = gsrc[idx]; }
    __syncthreads();

    const float* CF  = (const float*)wsv + COEF_OFF_F;   // GLOBAL (L1-resident, VMEM pipe)
    const float* BOg = (const float*)wsv + BOUT_OFF_F;
    const float bo[3] = {BOg[0], BOg[1], BOg[2]};

    const int lane = tid & 63;
    const int wid  = tid >> 6;                 // 0..3
    const int b    = lane & 15;
    const int q    = lane >> 4;
    const int rowbase = blockIdx.x * 128 + wid * 32;

    // ---- h0 (bf16-packed, D-layout: lane holds h[16t+4q+r] for col b) ----
    uint hpk[2][6][2];
    #pragma unroll
    for (int nt = 0; nt < 2; ++nt) {
        int row = rowbase + nt * 16 + b;
        #pragma unroll
        for (int t = 0; t < 6; ++t) {
            const float* src = (t < 3) ? (past + (size_t)row * 48 + t * 16 + q * 4)
                                       : (fut  + (size_t)row * 48 + (t - 3) * 16 + q * 4);
            f32x4 v = *(const f32x4*)src;
            hpk[nt][t][0] = packbf(v[0], v[1]);
            hpk[nt][t][1] = packbf(v[2], v[3]);
        }
    }

    // ---- intra-wave exchange: D-layout hpk -> B-fragments ----
    const int idxA = 4 * (b | ((((q << 1) + 0) & 3) << 4));
    const int idxB = 4 * (b | ((((q << 1) + 1) & 3) << 4));
    uint4 bfu[2][3];
    auto do_exchange = [&]() {
        #pragma unroll
        for (int nt = 0; nt < 2; ++nt)
            #pragma unroll
            for (int c = 0; c < 3; ++c)
                #pragma unroll
                for (int dd = 0; dd < 4; ++dd) {
                    int idx = (dd < 2) ? idxA : idxB;
                    int va = __builtin_amdgcn_ds_bpermute(idx, (int)hpk[nt][2 * c][dd & 1]);
                    int vb = __builtin_amdgcn_ds_bpermute(idx, (int)hpk[nt][2 * c + 1][dd & 1]);
                    bfu[nt][c][dd] = (uint)((lane < 32) ? va : vb);
                }
    };
    do_exchange();

    // ---- p0 ----
    float pc[2][3];
    #pragma unroll
    for (int nt = 0; nt < 2; ++nt) {
        int row = rowbase + nt * 16 + b;
        pc[nt][0] = last_pos[(size_t)row * 3 + 0];
        pc[nt][1] = last_pos[(size_t)row * 3 + 1];
        pc[nt][2] = last_pos[(size_t)row * 3 + 2];
    }

    const f32x4 zero4 = {0.f, 0.f, 0.f, 0.f};
    const int p0r = (0 + q) & 3, p1r = (1 + q) & 3, p2r = (2 + q) & 3, p3r = (3 + q) & 3;

    // tile-18 mini-GEMM (p-path), both col-groups
    auto tile18 = [&](f32x4* a18) {
        #pragma unroll
        for (int c = 0; c < 3; ++c) {
            bf16x8 a = __builtin_bit_cast(bf16x8, sb[(18 * 3 + c) * 64 + lane]);
            #pragma unroll
            for (int nt = 0; nt < 2; ++nt) {
                bf16x8 bb = __builtin_bit_cast(bf16x8, bfu[nt][c]);
                a18[nt] = __builtin_amdgcn_mfma_f32_16x16x32_bf16(a, bb, (c == 0) ? zero4 : a18[nt], 0, 0, 0);
            }
        }
    };

    // 6 gate groups; FIRST selects the (compile-time) step-0 correction path
    auto do_groups = [&](auto FIRST_c, const float (*d0)[3]) {
        constexpr bool FIRST = decltype(FIRST_c)::value;
        #pragma unroll
        for (int t = 0; t < 6; ++t) {
            f32x4 aR[2], aZ[2], aN[2];
            #pragma unroll
            for (int c = 0; c < 3; ++c) {
                bf16x8 fr = __builtin_bit_cast(bf16x8, sb[((t)      * 3 + c) * 64 + lane]);
                bf16x8 fz = __builtin_bit_cast(bf16x8, sb[((6 + t)  * 3 + c) * 64 + lane]);
                bf16x8 fn = __builtin_bit_cast(bf16x8, sb[((12 + t) * 3 + c) * 64 + lane]);
                #pragma unroll
                for (int nt = 0; nt < 2; ++nt) {
                    bf16x8 bb = __builtin_bit_cast(bf16x8, bfu[nt][c]);
                    aR[nt] = __builtin_amdgcn_mfma_f32_16x16x32_bf16(fr, bb, (c == 0) ? zero4 : aR[nt], 0, 0, 0);
                    aZ[nt] = __builtin_amdgcn_mfma_f32_16x16x32_bf16(fz, bb, (c == 0) ? zero4 : aZ[nt], 0, 0, 0);
                    aN[nt] = __builtin_amdgcn_mfma_f32_16x16x32_bf16(fn, bb, (c == 0) ? zero4 : aN[nt], 0, 0, 0);
                }
            }
            const float* cbase = CF + (16 * t + 4 * q) * 16;   // GLOBAL coeff rows (L1)
            uint np[2][2] = {{0u, 0u}, {0u, 0u}};
            #pragma unroll
            for (int r = 0; r < 4; ++r) {
                f32x4 ca = *(const f32x4*)(cbase + 16 * r + 4 * p0r);
                f32x4 cb = *(const f32x4*)(cbase + 16 * r + 4 * p1r);
                #pragma unroll
                for (int nt = 0; nt < 2; ++nt) {
                    float sr  = aR[nt][r] + cb[1];
                    float sz  = aZ[nt][r] + cb[2];
                    float ghn = aN[nt][r] + cb[0];
                    float gxn = ca[3] + pc[nt][0]*ca[0] + pc[nt][1]*ca[1] + pc[nt][2]*ca[2];
                    if constexpr (FIRST) {
                        f32x4 c2 = *(const f32x4*)(cbase + 16 * r + 4 * p2r);
                        f32x4 c3 = *(const f32x4*)(cbase + 16 * r + 4 * p3r);
                        sr += d0[nt][0]*c2[0] + d0[nt][1]*c2[1] + d0[nt][2]*c2[2];
                        sz += d0[nt][0]*c2[3] + d0[nt][1]*c3[0] + d0[nt][2]*c3[1];
                    }
                    float rg = sigm2(sr);
                    float zg = sigm2(sz);
                    float ng = tanh2(gxn + rg * ghn);
                    uint pk = hpk[nt][t][r >> 1];
                    float hold = __builtin_bit_cast(float, (r & 1) ? (pk & 0xffff0000u) : (pk << 16));
                    float hv = ng + zg * (hold - ng);
                    ushort hb = __builtin_bit_cast(ushort, __float2bfloat16(hv));
                    np[nt][r >> 1] |= (uint)hb << (16 * (r & 1));
                }
            }
            #pragma unroll
            for (int nt = 0; nt < 2; ++nt) {
                hpk[nt][t][0] = np[nt][0];
                hpk[nt][t][1] = np[nt][1];
            }
            __builtin_amdgcn_sched_barrier(0);
        }
    };

    // ================= peeled step 0 (has the folding correction) =================
    {
        f32x4 a18[2];
        tile18(a18);
        float d0[2][3];
        #pragma unroll
        for (int nt = 0; nt < 2; ++nt)
            #pragma unroll
            for (int o = 0; o < 3; ++o) {
                float po = a18[nt][o] + bo[o];
                float pb = __builtin_bit_cast(float,
                            __builtin_amdgcn_ds_bpermute(4 * b, __builtin_bit_cast(int, po)));
                d0[nt][o] = pc[nt][o] - pb;    // p0 - p~0
            }
        __builtin_amdgcn_sched_barrier(0);
        do_groups(std::integral_constant<bool, true>{}, d0);
        do_exchange();
    }

    // ================= steady loop s = 1..47 (no correction, no branches) =========
    #pragma unroll 1
    for (int s = 1; s < SEQ_LEN; ++s) {
        f32x4 a18[2];
        tile18(a18);
        #pragma unroll
        for (int nt = 0; nt < 2; ++nt)
            #pragma unroll
            for (int o = 0; o < 3; ++o) {
                float po = a18[nt][o] + bo[o];
                float pb = __builtin_bit_cast(float,
                            __builtin_amdgcn_ds_bpermute(4 * b, __builtin_bit_cast(int, po)));
                if (q == 0) {
                    int row = rowbase + nt * 16 + b;
                    out[((size_t)(s - 1) * NB + row) * 3 + o] = po;
                }
                pc[nt][o] = pb;
            }
        __builtin_amdgcn_sched_barrier(0);
        do_groups(std::integral_constant<bool, false>{}, nullptr);
        do_exchange();
    }

    // ================= final: rel_pos_47 ==========================================
    {
        f32x4 f18[2];
        tile18(f18);
        if (q == 0) {
            #pragma unroll
            for (int nt = 0; nt < 2; ++nt) {
                int row = rowbase + nt * 16 + b;
                #pragma unroll
                for (int o = 0; o < 3; ++o)
                    out[((size_t)47 * NB + row) * 3 + o] = f18[nt][o] + bo[o];
            }
        }
    }
}

extern "C" void kernel_launch(void* const* d_in, const int* in_sizes, int n_in,
                              void* d_out, int out_size, void* d_ws, size_t ws_size,
                              hipStream_t stream)
{
    const float* last_pos = (const float*)d_in[0];
    const float* past     = (const float*)d_in[1];
    const float* fut      = (const float*)d_in[2];
    const float* W_emb    = (const float*)d_in[3];
    const float* b_emb    = (const float*)d_in[4];
    const float* W_ih     = (const float*)d_in[5];
    const float* W_hh     = (const float*)d_in[6];
    const float* b_ih     = (const float*)d_in[7];
    const float* b_hh     = (const float*)d_in[8];
    const float* W_out    = (const float*)d_in[9];
    const float* b_out    = (const float*)d_in[10];
    float* out = (float*)d_out;

    hipLaunchKernelGGL(fold_k, dim3(5), dim3(64), 0, stream,
                       W_emb, b_emb, W_ih, W_hh, b_ih, b_hh, W_out, b_out, d_ws);
    hipLaunchKernelGGL(gru_mfma, dim3(NB / 128), dim3(256), 0, stream,
                       last_pos, past, fut, d_ws, out);
}

// Round 12
// 947.233 us; speedup vs baseline: 1.0147x; 1.0147x over previous
//
#include <hip/hip_runtime.h>
#include <hip/hip_bf16.h>
#include <type_traits>

#define SEQ_LEN 48
#define HID     96
#define NB      131072
#define MROWS   304                    // 288 gate rows + 3 W_out rows + 13 zero pad (19 tiles, LDS)
#define ABYTES  (MROWS*HID*2)          // 58368 B of bf16 A-fragments (LDS-staged)
#define A_U4    (ABYTES/16)            // 3648 uint4
#define GX_OFF_U4 3648                 // gxn fragments: 6 tiles, global-read (18432 B)
#define CB_OFF_F  19200                // cb quads: 96*4 floats (byte 76800)
#define PE_OFF_F  19584                // peel quads: 96*12 floats
#define BO_OFF_F  20736                // b_out: 3 floats

typedef __attribute__((ext_vector_type(4))) float f32x4;
typedef __attribute__((ext_vector_type(8))) __bf16 bf16x8;
typedef unsigned int uint;
typedef unsigned short ushort;

__device__ __forceinline__ float sigm2(float xp) {
    return __builtin_amdgcn_rcpf(1.f + __builtin_amdgcn_exp2f(-xp));   // inf-safe
}
__device__ __forceinline__ float tanh2(float yp) {
    return 1.f - 2.f * __builtin_amdgcn_rcpf(__builtin_amdgcn_exp2f(yp) + 1.f);  // inf-safe
}
__device__ __forceinline__ uint packbf(float a, float b) {
    ushort lo = __builtin_bit_cast(ushort, __float2bfloat16(a));
    ushort hi = __builtin_bit_cast(ushort, __float2bfloat16(b));
    return (uint)lo | ((uint)hi << 16);
}

// ---------------- weight folding: r/z/gxn all folded through W_out ------------------------
__global__ void fold_k(const float* __restrict__ W_emb, const float* __restrict__ b_emb,
                       const float* __restrict__ W_ih,  const float* __restrict__ W_hh,
                       const float* __restrict__ b_ih,  const float* __restrict__ b_hh,
                       const float* __restrict__ W_out, const float* __restrict__ b_out,
                       void* wsv)
{
    const float L2E  = 1.44269504088896340736f;
    const float L2E2 = 2.f * L2E;
    ushort* A   = (ushort*)wsv;
    ushort* GXu = (ushort*)wsv + ABYTES/2;          // gxn fragment region
    float*  CB  = (float*)wsv + CB_OFF_F;
    float*  PE  = (float*)wsv + PE_OFF_F;
    float*  BO  = (float*)wsv + BO_OFF_F;
    int g = blockIdx.x * 64 + threadIdx.x;
    if (g < 3) BO[g] = b_out[g];

    auto wxe_row = [&](int gg, float* w, float& bx) {
        w[0] = w[1] = w[2] = 0.f; bx = b_ih[gg];
        for (int e = 0; e < 32; e++) {
            float wi = W_ih[gg * 32 + e];
            w[0] += wi * W_emb[e * 3 + 0];
            w[1] += wi * W_emb[e * 3 + 1];
            w[2] += wi * W_emb[e * 3 + 2];
            bx   += wi * b_emb[e];
        }
    };

    if (g < MROWS) {
        float w[3] = {0.f, 0.f, 0.f}, bx = 0.f;
        if (g < 192) wxe_row(g, w, bx);
        for (int k = 0; k < HID; k++) {
            float val;
            if      (g < 192) val = (W_hh[g * HID + k] + w[0]*W_out[0*HID+k] + w[1]*W_out[1*HID+k] + w[2]*W_out[2*HID+k]) * L2E;
            else if (g < 288) val = W_hh[g * HID + k] * L2E2;
            else if (g < 291) val = W_out[(g - 288) * HID + k];
            else              val = 0.f;
            int t = g >> 4, c = k >> 5, l = (g & 15) | (((k >> 3) & 3) << 4), i = k & 7;
            A[((t * 3 + c) * 64 + l) * 8 + i] = __builtin_bit_cast(ushort, __float2bfloat16(val));
        }
    }
    if (g < 96) {
        int j = g;
        float wn[3], bxn; wxe_row(192 + j, wn, bxn);
        float wr[3], bxr; wxe_row(j,        wr, bxr);
        float wz[3], bxz; wxe_row(96 + j,   wz, bxz);
        // gxn fragment rows: (wn_j . W_out) * 2*log2e
        for (int k = 0; k < HID; k++) {
            float v = L2E2 * (wn[0]*W_out[0*HID+k] + wn[1]*W_out[1*HID+k] + wn[2]*W_out[2*HID+k]);
            int t2 = j >> 4, c = k >> 5, l = (j & 15) | (((k >> 3) & 3) << 4), i = k & 7;
            GXu[((t2 * 3 + c) * 64 + l) * 8 + i] = __builtin_bit_cast(ushort, __float2bfloat16(v));
        }
        // steady-state coeff quad
        CB[j*4 + 0] = b_hh[192 + j] * L2E2;                                                   // bhhn
        CB[j*4 + 1] = (bxr + b_hh[j]      + wr[0]*b_out[0] + wr[1]*b_out[1] + wr[2]*b_out[2]) * L2E;   // bsr
        CB[j*4 + 2] = (bxz + b_hh[96 + j] + wz[0]*b_out[0] + wz[1]*b_out[1] + wz[2]*b_out[2]) * L2E;   // bsz
        CB[j*4 + 3] = (bxn + wn[0]*b_out[0] + wn[1]*b_out[1] + wn[2]*b_out[2]) * L2E2;        // bgxn
        // peel-only correction coeffs
        PE[j*12 + 0] = wr[0]*L2E;  PE[j*12 + 1] = wr[1]*L2E;  PE[j*12 + 2] = wr[2]*L2E;  PE[j*12 + 3] = wz[0]*L2E;
        PE[j*12 + 4] = wz[1]*L2E;  PE[j*12 + 5] = wz[2]*L2E;  PE[j*12 + 6] = wn[0]*L2E2; PE[j*12 + 7] = wn[1]*L2E2;
        PE[j*12 + 8] = wn[2]*L2E2; PE[j*12 + 9] = 0.f;        PE[j*12 +10] = 0.f;        PE[j*12 +11] = 0.f;
    }
}

// ---------------- main kernel: gxn folded into GEMM; steady loop has no p dependency -----
__global__ __launch_bounds__(256, 2)
void gru_mfma(const float* __restrict__ last_pos, const float* __restrict__ past,
              const float* __restrict__ fut, const void* __restrict__ wsv,
              float* __restrict__ out)
{
    __shared__ uint4 sb[A_U4];                 // 58368 B: 19 A-tiles
    const int tid = threadIdx.x;
    const uint4* gsrc = (const uint4*)wsv;
    #pragma unroll
    for (int it = 0; it < 15; ++it) { int idx = tid + it * 256; if (idx < A_U4) sb[idx] = gsrc[idx]; }
    __syncthreads();

    const uint4* GX  = (const uint4*)wsv + GX_OFF_U4;    // gxn tiles (L1/L2)
    const float* CBg = (const float*)wsv + CB_OFF_F;
    const float* PEg = (const float*)wsv + PE_OFF_F;
    const float* BOg = (const float*)wsv + BO_OFF_F;
    const float bo[3] = {BOg[0], BOg[1], BOg[2]};

    const int lane = tid & 63;
    const int wid  = tid >> 6;                 // 0..3
    const int b    = lane & 15;
    const int q    = lane >> 4;
    const int rowbase = blockIdx.x * 128 + wid * 32;

    // ---- h0 (bf16-packed, D-layout) ----
    uint hpk[2][6][2];
    #pragma unroll
    for (int nt = 0; nt < 2; ++nt) {
        int row = rowbase + nt * 16 + b;
        #pragma unroll
        for (int t = 0; t < 6; ++t) {
            const float* src = (t < 3) ? (past + (size_t)row * 48 + t * 16 + q * 4)
                                       : (fut  + (size_t)row * 48 + (t - 3) * 16 + q * 4);
            f32x4 v = *(const f32x4*)src;
            hpk[nt][t][0] = packbf(v[0], v[1]);
            hpk[nt][t][1] = packbf(v[2], v[3]);
        }
    }

    // ---- intra-wave exchange: D-layout hpk -> B-fragments ----
    const int idxA = 4 * (b | ((((q << 1) + 0) & 3) << 4));
    const int idxB = 4 * (b | ((((q << 1) + 1) & 3) << 4));
    uint4 bfu[2][3];
    auto do_exchange = [&]() {
        #pragma unroll
        for (int nt = 0; nt < 2; ++nt)
            #pragma unroll
            for (int c = 0; c < 3; ++c)
                #pragma unroll
                for (int dd = 0; dd < 4; ++dd) {
                    int idx = (dd < 2) ? idxA : idxB;
                    int va = __builtin_amdgcn_ds_bpermute(idx, (int)hpk[nt][2 * c][dd & 1]);
                    int vb = __builtin_amdgcn_ds_bpermute(idx, (int)hpk[nt][2 * c + 1][dd & 1]);
                    bfu[nt][c][dd] = (uint)((lane < 32) ? va : vb);
                }
    };
    do_exchange();

    const f32x4 zero4 = {0.f, 0.f, 0.f, 0.f};

    // tile-18 mini-GEMM (output path only; NOT on the recurrence critical path)
    auto tile18 = [&](f32x4* a18) {
        #pragma unroll
        for (int c = 0; c < 3; ++c) {
            bf16x8 a = __builtin_bit_cast(bf16x8, sb[(18 * 3 + c) * 64 + lane]);
            #pragma unroll
            for (int nt = 0; nt < 2; ++nt) {
                bf16x8 bb = __builtin_bit_cast(bf16x8, bfu[nt][c]);
                a18[nt] = __builtin_amdgcn_mfma_f32_16x16x32_bf16(a, bb, (c == 0) ? zero4 : a18[nt], 0, 0, 0);
            }
        }
    };

    // 6 gate groups; 4 accumulators {r,z,ghn,gxn}; FIRST adds step-0 corrections
    auto do_groups = [&](auto FIRST_c, const float (*d0)[3]) {
        constexpr bool FIRST = decltype(FIRST_c)::value;
        #pragma unroll
        for (int t = 0; t < 6; ++t) {
            f32x4 aR[2], aZ[2], aN[2], aX[2];
            #pragma unroll
            for (int c = 0; c < 3; ++c) {
                bf16x8 fr = __builtin_bit_cast(bf16x8, sb[((t)      * 3 + c) * 64 + lane]);
                bf16x8 fz = __builtin_bit_cast(bf16x8, sb[((6 + t)  * 3 + c) * 64 + lane]);
                bf16x8 fn = __builtin_bit_cast(bf16x8, sb[((12 + t) * 3 + c) * 64 + lane]);
                bf16x8 fx = __builtin_bit_cast(bf16x8, GX[(t * 3 + c) * 64 + lane]);
                #pragma unroll
                for (int nt = 0; nt < 2; ++nt) {
                    bf16x8 bb = __builtin_bit_cast(bf16x8, bfu[nt][c]);
                    aR[nt] = __builtin_amdgcn_mfma_f32_16x16x32_bf16(fr, bb, (c == 0) ? zero4 : aR[nt], 0, 0, 0);
                    aZ[nt] = __builtin_amdgcn_mfma_f32_16x16x32_bf16(fz, bb, (c == 0) ? zero4 : aZ[nt], 0, 0, 0);
                    aN[nt] = __builtin_amdgcn_mfma_f32_16x16x32_bf16(fn, bb, (c == 0) ? zero4 : aN[nt], 0, 0, 0);
                    aX[nt] = __builtin_amdgcn_mfma_f32_16x16x32_bf16(fx, bb, (c == 0) ? zero4 : aX[nt], 0, 0, 0);
                }
            }
            uint np[2][2] = {{0u, 0u}, {0u, 0u}};
            #pragma unroll
            for (int r = 0; r < 4; ++r) {
                int j = 16 * t + 4 * q + r;
                f32x4 cbq = *(const f32x4*)(CBg + j * 4);
                f32x4 pe0, pe1, pe2;
                if constexpr (FIRST) {
                    pe0 = *(const f32x4*)(PEg + j * 12);
                    pe1 = *(const f32x4*)(PEg + j * 12 + 4);
                    pe2 = *(const f32x4*)(PEg + j * 12 + 8);
                }
                #pragma unroll
                for (int nt = 0; nt < 2; ++nt) {
                    float sr  = aR[nt][r] + cbq[1];
                    float sz  = aZ[nt][r] + cbq[2];
                    float ghn = aN[nt][r] + cbq[0];
                    float gxn = aX[nt][r] + cbq[3];
                    if constexpr (FIRST) {
                        sr  += d0[nt][0]*pe0[0] + d0[nt][1]*pe0[1] + d0[nt][2]*pe0[2];
                        sz  += d0[nt][0]*pe0[3] + d0[nt][1]*pe1[0] + d0[nt][2]*pe1[1];
                        gxn += d0[nt][0]*pe1[2] + d0[nt][1]*pe1[3] + d0[nt][2]*pe2[0];
                    }
                    float rg = sigm2(sr);
                    float zg = sigm2(sz);
                    float ng = tanh2(gxn + rg * ghn);
                    uint pk = hpk[nt][t][r >> 1];
                    float hold = __builtin_bit_cast(float, (r & 1) ? (pk & 0xffff0000u) : (pk << 16));
                    float hv = ng + zg * (hold - ng);
                    ushort hb = __builtin_bit_cast(ushort, __float2bfloat16(hv));
                    np[nt][r >> 1] |= (uint)hb << (16 * (r & 1));
                }
            }
            #pragma unroll
            for (int nt = 0; nt < 2; ++nt) {
                hpk[nt][t][0] = np[nt][0];
                hpk[nt][t][1] = np[nt][1];
            }
            __builtin_amdgcn_sched_barrier(0);
        }
    };

    // ================= peeled step 0 (folding correction via d0) ==================
    {
        float pc[2][3];
        #pragma unroll
        for (int nt = 0; nt < 2; ++nt) {
            int row = rowbase + nt * 16 + b;
            pc[nt][0] = last_pos[(size_t)row * 3 + 0];
            pc[nt][1] = last_pos[(size_t)row * 3 + 1];
            pc[nt][2] = last_pos[(size_t)row * 3 + 2];
        }
        f32x4 a18[2];
        tile18(a18);
        float d0[2][3];
        #pragma unroll
        for (int nt = 0; nt < 2; ++nt)
            #pragma unroll
            for (int o = 0; o < 3; ++o) {
                float po = a18[nt][o] + bo[o];
                float pb = __builtin_bit_cast(float,
                            __builtin_amdgcn_ds_bpermute(4 * b, __builtin_bit_cast(int, po)));
                d0[nt][o] = pc[nt][o] - pb;    // p0 - p~0
            }
        __builtin_amdgcn_sched_barrier(0);
        do_groups(std::integral_constant<bool, true>{}, d0);
        do_exchange();
    }

    // ================= steady loop s = 1..47 (no p dependency at all) =============
    #pragma unroll 1
    for (int s = 1; s < SEQ_LEN; ++s) {
        f32x4 a18[2];
        tile18(a18);
        if (q == 0) {
            #pragma unroll
            for (int nt = 0; nt < 2; ++nt) {
                int row = rowbase + nt * 16 + b;
                #pragma unroll
                for (int o = 0; o < 3; ++o)
                    out[((size_t)(s - 1) * NB + row) * 3 + o] = a18[nt][o] + bo[o];
            }
        }
        __builtin_amdgcn_sched_barrier(0);
        do_groups(std::integral_constant<bool, false>{}, nullptr);
        do_exchange();
    }

    // ================= final: rel_pos_47 ==========================================
    {
        f32x4 f18[2];
        tile18(f18);
        if (q == 0) {
            #pragma unroll
            for (int nt = 0; nt < 2; ++nt) {
                int row = rowbase + nt * 16 + b;
                #pragma unroll
                for (int o = 0; o < 3; ++o)
                    out[((size_t)47 * NB + row) * 3 + o] = f18[nt][o] + bo[o];
            }
        }
    }
}

extern "C" void kernel_launch(void* const* d_in, const int* in_sizes, int n_in,
                              void* d_out, int out_size, void* d_ws, size_t ws_size,
                              hipStream_t stream)
{
    const float* last_pos = (const float*)d_in[0];
    const float* past     = (const float*)d_in[1];
    const float* fut      = (const float*)d_in[2];
    const float* W_emb    = (const float*)d_in[3];
    const float* b_emb    = (const float*)d_in[4];
    const float* W_ih     = (const float*)d_in[5];
    const float* W_hh     = (const float*)d_in[6];
    const float* b_ih     = (const float*)d_in[7];
    const float* b_hh     = (const float*)d_in[8];
    const float* W_out    = (const float*)d_in[9];
    const float* b_out    = (const float*)d_in[10];
    float* out = (float*)d_out;

    hipLaunchKernelGGL(fold_k, dim3(5), dim3(64), 0, stream,
                       W_emb, b_emb, W_ih, W_hh, b_ih, b_hh, W_out, b_out, d_ws);
    hipLaunchKernelGGL(gru_mfma, dim3(NB / 128), dim3(256), 0, stream,
                       last_pos, past, fut, d_ws, out);
}